// Round 13
// baseline (154.046 us; speedup 1.0000x reference)
//
#include <hip/hip_runtime.h>
#include <stdint.h>

// ChamferDistance2D: B=8, N=M=8192, fp32, scalar out.
// R13 = R12 (green, 133us) with ONE change: query1 uses 4 lanes per query.
// R12 accounting: harness floor ~55us (268MB 0xAA ws-poison fill @6.6TB/s
// = 40.5us, top dispatch, + launch gaps); query1 ~35-40us = dominant kernel,
// latency-bound (one thread walks ~9 dependent L2 loads, only 8 waves/CU).
// Fix: 2048 blocks (32 waves/CU = max), aligned lane-quads per query, lanes
// split the 3x3 cells (lane j: cells j, j+4, j+8), quad shfl_xor(1,2) min,
// leader does done-test / worklist push / block sum. Chain /3, TLP x4.
// Pipeline: memset counts -> hist -> prefix -> scatter -> query1 (3x3, ~95%
// finish; leftovers to worklist) -> query2 (one wave per leftover, full
// 8192-pt coalesced scan, exact) -> finalize (no same-address atomics).
// ws: counts 1MB @0, start 1MB @1M, cursor 1MB @2M, sorted 1MB @3M,
//     wl 512KB @4M, wl_count 4B @4.5M, partial @5M.

#define BATCH 8
#define NPTS  8192
#define TPB   256
#define GRID  128
#define G2    (GRID * GRID)
#define BOX   4.25f
#define H     0.06640625f        // 8.5/128, exact in binary
#define NSB   (2 * BATCH)
#define NQB   512                // hist/scatter blocks
#define NQ1B  2048               // query1 blocks (4 lanes/query)
#define NQ2B  2048               // query2 blocks
#define NPART (NQ1B + NQ2B)      // partial slots

__device__ inline float min3f(float a, float b, float c) {
    float d;
    asm("v_min3_f32 %0, %1, %2, %3" : "=v"(d) : "v"(a), "v"(b), "v"(c));
    return d;
}

__device__ inline int cellof(float v) {
    int c = (int)((v + BOX) * (1.0f / H));
    return min(max(c, 0), GRID - 1);
}

// grid = 512. Also zeroes wl_count (stream-ordered before query1).
__global__ void hist_k(const float2* __restrict__ p1, const float2* __restrict__ p2,
                       int* __restrict__ counts, int* __restrict__ wl_count) {
    int g = blockIdx.x * TPB + threadIdx.x;
    if (g == 0) *wl_count = 0;
    int side = g >> 16, b = (g >> 13) & 7, i = g & (NPTS - 1);
    float2 P = (side ? p2 : p1)[(size_t)b * NPTS + i];
    int cell = cellof(P.y) * GRID + cellof(P.x);
    atomicAdd(&counts[(side * BATCH + b) * G2 + cell], 1);
}

// grid = 16; block sb scans its 16384-cell grid -> start (excl), cursor copy
__global__ __launch_bounds__(TPB) void prefix_k(const int* __restrict__ counts,
                                                int* __restrict__ start,
                                                int* __restrict__ cursor) {
    __shared__ int psum[TPB];
    const int CPT = G2 / TPB;
    int base = blockIdx.x * G2;
    int t = threadIdx.x;
    int s = 0;
    for (int u = 0; u < CPT; ++u) s += counts[base + t * CPT + u];
    psum[t] = s;
    __syncthreads();
    for (int off = 1; off < TPB; off <<= 1) {
        int v = (t >= off) ? psum[t - off] : 0;
        __syncthreads();
        psum[t] += v;
        __syncthreads();
    }
    int run = psum[t] - s;
    for (int u = 0; u < CPT; ++u) {
        int idx = base + t * CPT + u;
        int c = counts[idx];
        start[idx] = run;
        cursor[idx] = run;
        run += c;
    }
}

// grid = 512
__global__ void scatter_k(const float2* __restrict__ p1, const float2* __restrict__ p2,
                          int* __restrict__ cursor, float2* __restrict__ sorted) {
    int g = blockIdx.x * TPB + threadIdx.x;
    int side = g >> 16, b = (g >> 13) & 7, i = g & (NPTS - 1);
    float2 P = (side ? p2 : p1)[(size_t)b * NPTS + i];
    int cell = cellof(P.y) * GRID + cellof(P.x);
    int sb = side * BATCH + b;
    int pos = atomicAdd(&cursor[sb * G2 + cell], 1);
    sorted[(size_t)sb * NPTS + pos] = P;
}

// grid = 2048. Aligned lane-quad per query; lanes split the 3x3 cells.
__global__ __launch_bounds__(TPB) void query1_k(const float2* __restrict__ sorted,
                                                const int* __restrict__ start,
                                                const int* __restrict__ counts,
                                                int* __restrict__ wl,
                                                int* __restrict__ wl_count,
                                                float* __restrict__ partial) {
    int g   = (blockIdx.x * TPB + threadIdx.x) >> 2;   // query id
    int sub = threadIdx.x & 3;
    int sb  = g >> 13;
    float2 q = sorted[g];                      // queries in sorted order
    int tg = sb ^ 8;                           // opposite side, same batch
    const float2* __restrict__ pts = sorted + (size_t)tg * NPTS;
    const int* __restrict__ st = start + tg * G2;
    const int* __restrict__ ct = counts + tg * G2;

    int cx = cellof(q.x), cy = cellof(q.y);
    float best = 3.0e38f;
#pragma unroll
    for (int c = 0; c < 9; ++c) {              // lane sub takes c % 4 == sub
        if ((c & 3) != sub && c != 8) continue;
        if (c == 8 && sub != 0) continue;      // cells {sub, sub+4} + lane0 gets 8
        int y = cy + c / 3 - 1, x = cx + c % 3 - 1;
        if (x < 0 || x > GRID - 1 || y < 0 || y > GRID - 1) continue;
        int cell = y * GRID + x;
        int s = st[cell];
        int e = s + ct[cell];
        for (int k = s; k < e; ++k) {
            float2 p = pts[k];
            float dx = q.x - p.x, dyv = q.y - p.y;
            best = fminf(best, fmaf(dx, dx, dyv * dyv));
        }
    }
    // quad min (xor 1,2 stay within the aligned quad)
    best = fminf(best, __shfl_xor(best, 1, 64));
    best = fminf(best, __shfl_xor(best, 2, 64));

    bool leader = (sub == 0);
    bool done = best <= H * H;                 // unscanned cells (ring>=2) are >= h away

    // wave-aggregated worklist push (leader lanes only)
    int lane = threadIdx.x & 63;
    unsigned long long mask = __ballot(leader && !done);
    int base = 0;
    if (lane == 0 && mask) base = atomicAdd(wl_count, __popcll(mask));
    base = __shfl(base, 0, 64);
    if (leader && !done) {
        int off = __popcll(mask & ((1ull << lane) - 1ull));
        wl[base + off] = g;
    }

    // block-sum finished contributions (leaders only) -> partial (no atomics)
    float d = (leader && done) ? best : 0.0f;
#pragma unroll
    for (int off = 32; off > 0; off >>= 1)
        d += __shfl_down(d, off, 64);
    __shared__ float wsum[TPB / 64];
    int w = threadIdx.x >> 6;
    if (lane == 0) wsum[w] = d;
    __syncthreads();
    if (threadIdx.x == 0)
        partial[blockIdx.x] = wsum[0] + wsum[1] + wsum[2] + wsum[3];
}

// grid = 2048 blocks = 8192 waves; ONE WAVE per leftover query, full 8192-pt
// coalesced scan. Block accumulates -> partial[NQ1B + blockIdx] (no atomics).
__global__ __launch_bounds__(TPB) void query2_k(const float2* __restrict__ sorted,
                                                const int* __restrict__ wl,
                                                const int* __restrict__ wl_count,
                                                float* __restrict__ partial) {
    int lane = threadIdx.x & 63;
    int wv = (blockIdx.x * TPB + threadIdx.x) >> 6;
    int nwaves = (gridDim.x * TPB) >> 6;
    int nwl = *wl_count;

    float acc = 0.0f;
    for (int widx = wv; widx < nwl; widx += nwaves) {
        int g = wl[widx];
        float2 q = sorted[g];
        const float2* __restrict__ pts = sorted + ((size_t)((g >> 13) ^ 8)) * NPTS;

        float best = 3.0e38f;
        for (int k0 = 0; k0 < NPTS; k0 += 256) {       // 128 pts/lane, unroll 4
            float2 p0 = pts[k0 + lane];
            float2 p1 = pts[k0 + 64 + lane];
            float2 p2 = pts[k0 + 128 + lane];
            float2 p3 = pts[k0 + 192 + lane];
            float dx0 = q.x - p0.x, dy0 = q.y - p0.y;
            float dx1 = q.x - p1.x, dy1 = q.y - p1.y;
            float dx2 = q.x - p2.x, dy2 = q.y - p2.y;
            float dx3 = q.x - p3.x, dy3 = q.y - p3.y;
            float d0 = fmaf(dx0, dx0, dy0 * dy0);
            float d1 = fmaf(dx1, dx1, dy1 * dy1);
            float d2 = fmaf(dx2, dx2, dy2 * dy2);
            float d3 = fmaf(dx3, dx3, dy3 * dy3);
            best = min3f(best, d0, d1);
            best = min3f(best, d2, d3);
        }
#pragma unroll
        for (int off = 1; off < 64; off <<= 1)
            best = fminf(best, __shfl_xor(best, off, 64));
        if (lane == 0) acc += best;
    }

    __shared__ float wsum[TPB / 64];
    int w = threadIdx.x >> 6;
    if (lane == 0) wsum[w] = acc;
    __syncthreads();
    if (threadIdx.x == 0)
        partial[NQ1B + blockIdx.x] = wsum[0] + wsum[1] + wsum[2] + wsum[3];
}

// 1 block: sum partials -> out (single plain store, no atomics anywhere)
__global__ __launch_bounds__(TPB) void finalize_k(const float* __restrict__ partial,
                                                  float* __restrict__ out) {
    int t = threadIdx.x;
    float s = 0.0f;
    for (int i = t; i < NPART; i += TPB) s += partial[i];
#pragma unroll
    for (int off = 32; off > 0; off >>= 1)
        s += __shfl_down(s, off, 64);
    __shared__ float wsum[TPB / 64];
    int lane = t & 63, w = t >> 6;
    if (lane == 0) wsum[w] = s;
    __syncthreads();
    if (t == 0)
        *out = (wsum[0] + wsum[1] + wsum[2] + wsum[3]) * (1.0f / NPTS);
}

extern "C" void kernel_launch(void* const* d_in, const int* in_sizes, int n_in,
                              void* d_out, int out_size, void* d_ws, size_t ws_size,
                              hipStream_t stream) {
    const float2* p1 = (const float2*)d_in[0];
    const float2* p2 = (const float2*)d_in[1];
    float* out = (float*)d_out;

    char* ws = (char*)d_ws;
    int*    counts  = (int*)(ws);
    int*    start   = (int*)(ws + (size_t)1 * 1024 * 1024);
    int*    cursor  = (int*)(ws + (size_t)2 * 1024 * 1024);
    float2* sorted  = (float2*)(ws + (size_t)3 * 1024 * 1024);
    int*    wl      = (int*)(ws + (size_t)4 * 1024 * 1024);
    int*    wl_cnt  = (int*)(ws + (size_t)4608 * 1024);
    float*  partial = (float*)(ws + (size_t)5 * 1024 * 1024);
    // ~5 MB total (>=20 MB proven available)

    hipMemsetAsync(counts, 0, (size_t)NSB * G2 * sizeof(int), stream);

    hist_k<<<NQB, TPB, 0, stream>>>(p1, p2, counts, wl_cnt);
    prefix_k<<<NSB, TPB, 0, stream>>>(counts, start, cursor);
    scatter_k<<<NQB, TPB, 0, stream>>>(p1, p2, cursor, sorted);
    query1_k<<<NQ1B, TPB, 0, stream>>>(sorted, start, counts, wl, wl_cnt, partial);
    query2_k<<<NQ2B, TPB, 0, stream>>>(sorted, wl, wl_cnt, partial);
    finalize_k<<<1, TPB, 0, stream>>>(partial, out);
}